// Round 7
// baseline (242.101 us; speedup 1.0000x reference)
//
#include <hip/hip_runtime.h>
#include <cstdint>
#include <cstddef>

#define S_LEN   2048
#define D_MODEL 1536
#define NH      24
#define HDIM    64
#define WINDOW  512
#define NANCH   4

typedef __attribute__((ext_vector_type(8))) short short8;
typedef __attribute__((ext_vector_type(4))) float floatx4;

#define ASYNC_COPY16(g, l) \
    __builtin_amdgcn_global_load_lds((const __attribute__((address_space(1))) uint32_t*)(g), \
                                     (__attribute__((address_space(3))) uint32_t*)(l), 16, 0, 0)

static __device__ __forceinline__ ushort f32_to_bf16(float f) {
    uint32_t u = __float_as_uint(f);
    uint32_t r = (u + 0x7FFFu + ((u >> 16) & 1u)) >> 16;
    return (ushort)r;
}

// ---------------- prep: RoPE cos/sin table + spike mask normalize (float) ----------------
__global__ __launch_bounds__(256) void prep_kernel(
    const uint8_t* __restrict__ raw, float* __restrict__ normf, float* __restrict__ cs) {
    if (blockIdx.x < 256) {
        int idx = blockIdx.x * 256 + threadIdx.x;   // 65536 = s*32 + i
        int s = idx >> 5, i = idx & 31;
        float inv_freq = expf(-(float)i * 0.2878231366242557f); // ln(10000)/32
        float c, sn;
        sincosf((float)s * inv_freq, &sn, &c);
        cs[s * 64 + i]      = c;
        cs[s * 64 + 32 + i] = sn;
        return;
    }
    __shared__ int sh[2];
    if (threadIdx.x == 0) { sh[0] = 0; sh[1] = 0; }
    __syncthreads();
    int f = 0, nz = 0;
    for (int i = threadIdx.x; i < S_LEN; i += 256) {
        uint8_t b = raw[i];
        if ((i & 3) == 3 && b == 0x3f) f++;          // 1.0f high byte
        if ((i & 3) != 0 && b != 0)    nz++;
    }
    if (f)  atomicAdd(&sh[0], f);
    if (nz) atomicAdd(&sh[1], nz);
    __syncthreads();
    const int mode = (sh[0] > 0) ? 2 : ((sh[1] > 0) ? 1 : 0);  // 2=f32 1=u8 0=i32
    for (int i = threadIdx.x; i < S_LEN; i += 256) {
        int v;
        if (mode == 2)      v = (((const float*)raw)[i] != 0.0f) ? 1 : 0;
        else if (mode == 1) v = raw[i] ? 1 : 0;
        else                v = (((const int*)raw)[i] != 0) ? 1 : 0;
        normf[i] = v ? 1.0f : 0.0f;
    }
}

// ---------------- fp32 -> bf16 convert: x + Wq + Wk + Wv in one launch ----------------
__global__ void f2bf4_kernel(const float* __restrict__ x,
                             const float* __restrict__ wq, const float* __restrict__ wk,
                             const float* __restrict__ wv,
                             ushort* __restrict__ xb, ushort* __restrict__ wb,
                             int xq4, int wq4) {
    const int which = blockIdx.y;
    const size_t w_elems = (size_t)D_MODEL * D_MODEL;
    const float* src; ushort* dst; int n4;
    if (which == 0)      { src = x;  dst = xb;               n4 = xq4; }
    else if (which == 1) { src = wq; dst = wb;               n4 = wq4; }
    else if (which == 2) { src = wk; dst = wb + w_elems;     n4 = wq4; }
    else                 { src = wv; dst = wb + 2 * w_elems; n4 = wq4; }
    int i = blockIdx.x * blockDim.x + threadIdx.x;
    if (i >= n4) return;
    float4 v = ((const float4*)src)[i];
    ushort4 o;
    o.x = f32_to_bf16(v.x);
    o.y = f32_to_bf16(v.y);
    o.z = f32_to_bf16(v.z);
    o.w = f32_to_bf16(v.w);
    ((ushort4*)dst)[i] = o;
}

// ---------------- QKV projection + fused RoPE ----------------
// z=0 -> Qb bf16 (roped, pre-scaled 0.125*log2e for exp2-domain softmax);
// z=1 -> Kb bf16 (roped); z=2 -> Vt bf16 [H][64][S]
__global__ __launch_bounds__(256) void gemm_qkv_kernel(
    const ushort* __restrict__ xb,   // [2048][1536] bf16
    const ushort* __restrict__ wb,   // [3][1536][1536] bf16
    const float*  __restrict__ cs,   // [2048][64] cos|sin table
    ushort* __restrict__ Qb, ushort* __restrict__ Kb, ushort* __restrict__ Vt)
{
    const int tm = blockIdx.x;
    const int tn = blockIdx.y;
    const int z  = blockIdx.z;
    const ushort* W = wb + (size_t)z * (D_MODEL * (size_t)D_MODEL);

    __shared__ __align__(16) ushort As[128 * 32];
    __shared__ __align__(16) ushort Bs[128 * 32];

    const int tid  = threadIdx.x;
    const int wave = tid >> 6;
    const int lane = tid & 63;

    const int srow = wave * 32 + (lane >> 2);
    const int scol = (lane & 3) * 8;
    const ushort* gA0 = xb + (size_t)(tm * 128 + srow) * D_MODEL + scol;
    const ushort* gA1 = gA0 + (size_t)16 * D_MODEL;
    const ushort* gB0 = W  + (size_t)(tn * 128 + srow) * D_MODEL + scol;
    const ushort* gB1 = gB0 + (size_t)16 * D_MODEL;
    ushort* lA0 = &As[wave * 1024];
    ushort* lA1 = &As[wave * 1024 + 512];
    ushort* lB0 = &Bs[wave * 1024];
    ushort* lB1 = &Bs[wave * 1024 + 512];

    const int wm = (wave >> 1) * 64;
    const int wn = (wave & 1) * 64;
    const int lrow  = lane & 15;
    const int quadk = (lane >> 4) * 8;

    floatx4 acc[4][4];
#pragma unroll
    for (int i = 0; i < 4; ++i)
#pragma unroll
        for (int j = 0; j < 4; ++j)
            acc[i][j] = (floatx4){0.f, 0.f, 0.f, 0.f};

    for (int kt = 0; kt < D_MODEL / 32; ++kt) {
        __syncthreads();
        ASYNC_COPY16(gA0 + kt * 32, lA0);
        ASYNC_COPY16(gA1 + kt * 32, lA1);
        ASYNC_COPY16(gB0 + kt * 32, lB0);
        ASYNC_COPY16(gB1 + kt * 32, lB1);
        __syncthreads();

        short8 af[4], bf[4];
#pragma unroll
        for (int i = 0; i < 4; ++i) af[i] = *(const short8*)(&As[(wm + i * 16 + lrow) * 32 + quadk]);
#pragma unroll
        for (int j = 0; j < 4; ++j) bf[j] = *(const short8*)(&Bs[(wn + j * 16 + lrow) * 32 + quadk]);
#pragma unroll
        for (int i = 0; i < 4; ++i)
#pragma unroll
            for (int j = 0; j < 4; ++j)
                acc[i][j] = __builtin_amdgcn_mfma_f32_16x16x32_bf16(af[i], bf[j], acc[i][j], 0, 0, 0);
    }

    const int r0 = (lane >> 4) * 4;
    const int c0 = lane & 15;
    if (z < 2) {
        ushort* O = (z == 0) ? Qb : Kb;
        // Q pre-scale: 0.125 (softmax) * log2(e) (exp2 domain)
        const float qscale = (z == 0) ? 0.18033688011112042f : 1.0f;
#pragma unroll
        for (int i = 0; i < 4; ++i) {
#pragma unroll
            for (int j = 0; j < 2; ++j) {
                const int col = tn * 128 + wn + j * 16 + c0;
                const int h = col >> 6, d0 = col & 63;
#pragma unroll
                for (int r = 0; r < 4; ++r) {
                    const int row = tm * 128 + wm + i * 16 + r0 + r;
                    const float c  = cs[row * 64 + d0];
                    const float sn = cs[row * 64 + 32 + d0];
                    const float x0 = acc[i][j][r];
                    const float x1 = acc[i][j + 2][r];
                    const size_t base = ((size_t)h * S_LEN + row) * HDIM;
                    O[base + d0]      = f32_to_bf16((x0 * c - x1 * sn) * qscale);
                    O[base + d0 + 32] = f32_to_bf16((x1 * c + x0 * sn) * qscale);
                }
            }
        }
    } else {
#pragma unroll
        for (int i = 0; i < 4; ++i) {
#pragma unroll
            for (int j = 0; j < 4; ++j) {
                int col = tn * 128 + wn + j * 16 + c0;
                int h = col >> 6, d = col & 63;
                int row0 = tm * 128 + wm + i * 16 + r0;
                ushort4 o;
                o.x = f32_to_bf16(acc[i][j][0]);
                o.y = f32_to_bf16(acc[i][j][1]);
                o.z = f32_to_bf16(acc[i][j][2]);
                o.w = f32_to_bf16(acc[i][j][3]);
                *(ushort4*)&Vt[((size_t)h * HDIM + d) * S_LEN + row0] = o;
            }
        }
    }
}

// ---------------- flash attention: S^T formulation ----------------
// S^T = K·Q^T so each lane owns ALL scores of one query (l16) -> softmax
// reduction is in-lane VALU + 2 shfls instead of 32 serial shfls.
// 2 k-tiles (128 keys) per round. Per-tile wave-uniform mask modes.
__global__ __launch_bounds__(256, 4) void flash_attn_kernel(
    const ushort* __restrict__ Qb,   // [H][S][64] bf16 roped, pre-scaled
    const ushort* __restrict__ Kb,   // [H][S][64] bf16 roped
    const ushort* __restrict__ Vt,   // [H][64][S] bf16
    const float* __restrict__ spikef,// [S] 0.0/1.0
    float* __restrict__ out)         // [S][1536]
{
    // XCD-aware remap: each XCD owns 3 whole heads (K/V set ~3MB < 4MB L2)
    const int lb  = blockIdx.x + (blockIdx.y << 5);  // 0..767
    const int h   = (lb & 7) * 3 + ((lb >> 3) >> 5);
    const int qt  = (lb >> 3) & 31;
    const int qs  = qt * 64;
    const int tid  = threadIdx.x;
    const int wave = tid >> 6;
    const int lane = tid & 63;
    const int quad = lane >> 4;
    const int l16  = lane & 15;

    __shared__ __align__(16) ushort Pst[4][16 * 136];   // per-wave P [q][k0..127], stride 136

    const size_t krow = (size_t)h * S_LEN;

    // Q B-fragments (n = q = l16)
    const ushort* Qp = Qb + (krow + qs + wave * 16 + l16) * HDIM + quad * 8;
    const short8 qf0 = *(const short8*)(Qp);
    const short8 qf1 = *(const short8*)(Qp + 32);

    const int q_lane = qs + wave * 16 + l16;   // the query this lane's softmax owns

    float m_i = -INFINITY, l_i = 0.f;
    floatx4 Oacc[4];
#pragma unroll
    for (int j2 = 0; j2 < 4; ++j2) Oacc[j2] = (floatx4){0.f, 0.f, 0.f, 0.f};

    const int lo = (qs > WINDOW ? qs - WINDOW : 0) >> 6;
    const int has_anchor = (lo > 0) ? 1 : 0;
    const int nt = (qt - lo + 1) + has_anchor;
    const int nr = (nt + 1) >> 1;

    ushort* myP = Pst[wave];

    for (int ri = 0; ri < nr; ++ri) {
        const int iA = 2 * ri, iB = 2 * ri + 1;
        const int tA = has_anchor ? (iA == 0 ? 0 : lo + iA - 1) : iA;
        const int liveB = (iB < nt) ? 1 : 0;
        const int tB = liveB ? (has_anchor ? (lo + iB - 1) : iB) : tA;

        // ---- S^T = K · Q^T : 8 frags (f<4: tile A, f>=4: tile B) ----
        floatx4 S[8];
        float4 sp[8];
#pragma unroll
        for (int f = 0; f < 8; ++f) {
            const int t = (f < 4) ? tA : tB;
            const int ks = t * 64 + (f & 3) * 16;
            const ushort* Kp = Kb + (krow + ks + l16) * HDIM + quad * 8;
            short8 kf0 = *(const short8*)(Kp);
            short8 kf1 = *(const short8*)(Kp + 32);
            sp[f] = *(const float4*)(spikef + ks + quad * 4);
            floatx4 a = (floatx4){0.f, 0.f, 0.f, 0.f};
            a = __builtin_amdgcn_mfma_f32_16x16x32_bf16(kf0, qf0, a, 0, 0, 0);
            a = __builtin_amdgcn_mfma_f32_16x16x32_bf16(kf1, qf1, a, 0, 0, 0);
            S[f] = a;
        }

        // ---- max over lane's 32 raw scores (valid superset: safe stabilizer) ----
        float fm[8];
#pragma unroll
        for (int f = 0; f < 8; ++f)
            fm[f] = fmaxf(fmaxf(S[f][0], S[f][1]), fmaxf(S[f][2], S[f][3]));
        float mx = fmaxf(fmaxf(fmaxf(fm[0], fm[1]), fmaxf(fm[2], fm[3])),
                         fmaxf(fmaxf(fm[4], fm[5]), fmaxf(fm[6], fm[7])));
        mx = fmaxf(mx, __shfl_xor(mx, 16));
        mx = fmaxf(mx, __shfl_xor(mx, 32));
        const float mnew = fmaxf(m_i, mx);
        const float aexp = exp2f(m_i - mnew);   // m_i=-inf first round -> 0

        // ---- masks (wave-uniform mode per tile) + exp2 + weights ----
        // mode: 0=interior 1=diag(k<=q) 2=window-edge 3=anchor(k<4) 4=dead
        int modeA, modeB;
        {
            modeA = (tA == qt) ? 1 : ((has_anchor && tA == 0) ? 3 :
                    ((qs + 63 - tA * 64 > WINDOW) ? 2 : 0));
            modeB = !liveB ? 4 : ((tB == qt) ? 1 : ((has_anchor && tB == 0) ? 3 :
                    ((qs + 63 - tB * 64 > WINDOW) ? 2 : 0)));
        }
        float rsum = 0.f;
#pragma unroll
        for (int f = 0; f < 8; ++f) {
            const int t = (f < 4) ? tA : tB;
            const int mode = (f < 4) ? modeA : modeB;
            const int kb = t * 64 + (f & 3) * 16 + quad * 4;
#pragma unroll
            for (int r = 0; r < 4; ++r) {
                const int k = kb + r;
                float v;
                if (mode == 0)      v = 1.f;
                else if (mode == 1) v = (k <= q_lane) ? 1.f : 0.f;
                else if (mode == 2) v = ((k >= q_lane - WINDOW) || (k < NANCH)) ? 1.f : 0.f;
                else if (mode == 3) v = (k < NANCH) ? 1.f : 0.f;
                else                v = 0.f;
                const float sv = (r == 0) ? sp[f].x : (r == 1) ? sp[f].y : (r == 2) ? sp[f].z : sp[f].w;
                const float w = exp2f(S[f][r] - mnew) * v * sv;
                S[f][r] = w;
                rsum += w;
            }
        }
        rsum += __shfl_xor(rsum, 16);
        rsum += __shfl_xor(rsum, 32);
        l_i = l_i * aexp + rsum;
        m_i = mnew;

        // ---- redistribute alpha to O C-layout rows (q = quad*4+r) ----
        float ar[4];
#pragma unroll
        for (int r = 0; r < 4; ++r)
            ar[r] = __int_as_float(__builtin_amdgcn_ds_bpermute((quad * 4 + r) * 4,
                                                                __float_as_int(aexp)));
#pragma unroll
        for (int j2 = 0; j2 < 4; ++j2)
#pragma unroll
            for (int r = 0; r < 4; ++r)
                Oacc[j2][r] *= ar[r];

        // ---- pack P (bf16 truncation) -> LDS [q=l16][kcol], 8 x b64 ----
#pragma unroll
        for (int f = 0; f < 8; ++f) {
            uint32_t p01 = (__float_as_uint(S[f][0]) >> 16) | (__float_as_uint(S[f][1]) & 0xFFFF0000u);
            uint32_t p23 = (__float_as_uint(S[f][2]) >> 16) | (__float_as_uint(S[f][3]) & 0xFFFF0000u);
            uint2 pk; pk.x = p01; pk.y = p23;
            *(uint2*)(myP + l16 * 136 + f * 16 + quad * 4) = pk;
        }

        // ---- P @ V : O[q][d] += P[q][k] V[k][d] ----
#pragma unroll
        for (int c = 0; c < 4; ++c) {
            const short8 pA = *(const short8*)(myP + l16 * 136 + c * 32 + quad * 8);
            const int kg = ((c < 2) ? (tA * 64 + c * 32) : (tB * 64 + (c - 2) * 32)) + quad * 8;
#pragma unroll
            for (int j2 = 0; j2 < 4; ++j2) {
                const short8 vf = *(const short8*)(Vt + ((size_t)h * HDIM + j2 * 16 + l16) * S_LEN + kg);
                Oacc[j2] = __builtin_amdgcn_mfma_f32_16x16x32_bf16(pA, vf, Oacc[j2], 0, 0, 0);
            }
        }
    }

    // ---- epilogue ----
    float linv[4];
#pragma unroll
    for (int r = 0; r < 4; ++r) {
        const float lr = __int_as_float(__builtin_amdgcn_ds_bpermute((quad * 4 + r) * 4,
                                                                     __float_as_int(l_i)));
        const int qrow = qs + wave * 16 + quad * 4 + r;
        linv[r] = (lr > 0.f && spikef[qrow] != 0.f) ? (1.0f / lr) : 0.f;
    }
#pragma unroll
    for (int r = 0; r < 4; ++r) {
        const int qrow = qs + wave * 16 + quad * 4 + r;
#pragma unroll
        for (int j2 = 0; j2 < 4; ++j2)
            out[(size_t)qrow * D_MODEL + h * HDIM + j2 * 16 + l16] = Oacc[j2][r] * linv[r];
    }
}

extern "C" void kernel_launch(void* const* d_in, const int* in_sizes, int n_in,
                              void* d_out, int out_size, void* d_ws, size_t ws_size,
                              hipStream_t stream) {
    const float* x     = (const float*)d_in[0];
    const uint8_t* spike_raw = (const uint8_t*)d_in[1];
    const float* Wq    = (const float*)d_in[2];
    const float* Wk    = (const float*)d_in[3];
    const float* Wv    = (const float*)d_in[4];
    float* out = (float*)d_out;

    const size_t xb_elems = (size_t)S_LEN * D_MODEL;
    const size_t w_elems  = (size_t)D_MODEL * D_MODEL;
    const size_t hs_elems = (size_t)NH * S_LEN * HDIM;

    char* ws = (char*)d_ws;
    size_t off = 0;
    ushort* xb = (ushort*)(ws + off); off += xb_elems * 2;
    ushort* wb = (ushort*)(ws + off); off += 3 * w_elems * 2;
    ushort* Qb = (ushort*)(ws + off); off += hs_elems * 2;
    ushort* Kb = (ushort*)(ws + off); off += hs_elems * 2;
    ushort* Vt = (ushort*)(ws + off); off += hs_elems * 2;
    float*  cst = (float*)(ws + off); off += (size_t)S_LEN * 64 * 4;
    float* spike_f = (float*)(ws + off); off += S_LEN * 4;
    if (ws_size < off) return;

    // 0) RoPE table + spike normalize
    prep_kernel<<<257, 256, 0, stream>>>(spike_raw, spike_f, cst);

    // 1) fp32 -> bf16 (x, Wq, Wk, Wv)
    {
        int xq4 = (int)(xb_elems / 4);
        int wq4 = (int)(w_elems / 4);
        f2bf4_kernel<<<dim3((xq4 + 255) / 256, 4), 256, 0, stream>>>(
            x, Wq, Wk, Wv, xb, wb, xq4, wq4);
    }

    // 2) QKV projections + fused RoPE
    gemm_qkv_kernel<<<dim3(S_LEN / 128, D_MODEL / 128, 3), 256, 0, stream>>>(
        xb, wb, cst, Qb, Kb, Vt);

    // 3) flash attention (S^T formulation)
    flash_attn_kernel<<<dim3(S_LEN / 64, NH), 256, 0, stream>>>(Qb, Kb, Vt, spike_f, out);
}

// Round 8
// 236.630 us; speedup vs baseline: 1.0231x; 1.0231x over previous
//
#include <hip/hip_runtime.h>
#include <cstdint>
#include <cstddef>

#define S_LEN   2048
#define D_MODEL 1536
#define NH      24
#define HDIM    64
#define WINDOW  512
#define NANCH   4

typedef __attribute__((ext_vector_type(8))) short short8;
typedef __attribute__((ext_vector_type(4))) float floatx4;

#define ASYNC_COPY16(g, l) \
    __builtin_amdgcn_global_load_lds((const __attribute__((address_space(1))) uint32_t*)(g), \
                                     (__attribute__((address_space(3))) uint32_t*)(l), 16, 0, 0)

static __device__ __forceinline__ ushort f32_to_bf16(float f) {
    uint32_t u = __float_as_uint(f);
    uint32_t r = (u + 0x7FFFu + ((u >> 16) & 1u)) >> 16;
    return (ushort)r;
}

// ---------------- prep: RoPE cos/sin table + spike mask normalize (float) ----------------
__global__ __launch_bounds__(256) void prep_kernel(
    const uint8_t* __restrict__ raw, float* __restrict__ normf, float* __restrict__ cs) {
    if (blockIdx.x < 256) {
        int idx = blockIdx.x * 256 + threadIdx.x;   // 65536 = s*32 + i
        int s = idx >> 5, i = idx & 31;
        float inv_freq = expf(-(float)i * 0.2878231366242557f); // ln(10000)/32
        float c, sn;
        sincosf((float)s * inv_freq, &sn, &c);
        cs[s * 64 + i]      = c;
        cs[s * 64 + 32 + i] = sn;
        return;
    }
    __shared__ int sh[2];
    if (threadIdx.x == 0) { sh[0] = 0; sh[1] = 0; }
    __syncthreads();
    int f = 0, nz = 0;
    for (int i = threadIdx.x; i < S_LEN; i += 256) {
        uint8_t b = raw[i];
        if ((i & 3) == 3 && b == 0x3f) f++;          // 1.0f high byte
        if ((i & 3) != 0 && b != 0)    nz++;
    }
    if (f)  atomicAdd(&sh[0], f);
    if (nz) atomicAdd(&sh[1], nz);
    __syncthreads();
    const int mode = (sh[0] > 0) ? 2 : ((sh[1] > 0) ? 1 : 0);  // 2=f32 1=u8 0=i32
    for (int i = threadIdx.x; i < S_LEN; i += 256) {
        int v;
        if (mode == 2)      v = (((const float*)raw)[i] != 0.0f) ? 1 : 0;
        else if (mode == 1) v = raw[i] ? 1 : 0;
        else                v = (((const int*)raw)[i] != 0) ? 1 : 0;
        normf[i] = v ? 1.0f : 0.0f;
    }
}

// ---------------- fp32 -> bf16 convert: x + Wq + Wk + Wv in one launch ----------------
__global__ void f2bf4_kernel(const float* __restrict__ x,
                             const float* __restrict__ wq, const float* __restrict__ wk,
                             const float* __restrict__ wv,
                             ushort* __restrict__ xb, ushort* __restrict__ wb,
                             int xq4, int wq4) {
    const int which = blockIdx.y;
    const size_t w_elems = (size_t)D_MODEL * D_MODEL;
    const float* src; ushort* dst; int n4;
    if (which == 0)      { src = x;  dst = xb;               n4 = xq4; }
    else if (which == 1) { src = wq; dst = wb;               n4 = wq4; }
    else if (which == 2) { src = wk; dst = wb + w_elems;     n4 = wq4; }
    else                 { src = wv; dst = wb + 2 * w_elems; n4 = wq4; }
    int i = blockIdx.x * blockDim.x + threadIdx.x;
    if (i >= n4) return;
    float4 v = ((const float4*)src)[i];
    ushort4 o;
    o.x = f32_to_bf16(v.x);
    o.y = f32_to_bf16(v.y);
    o.z = f32_to_bf16(v.z);
    o.w = f32_to_bf16(v.w);
    ((ushort4*)dst)[i] = o;
}

// ---------------- QKV projection + fused RoPE ----------------
// z=0 -> Qb bf16 (roped, pre-scaled 0.125*log2e for exp2-domain softmax);
// z=1 -> Kb bf16 (roped); z=2 -> Vt bf16 [H][64][S]
__global__ __launch_bounds__(256) void gemm_qkv_kernel(
    const ushort* __restrict__ xb,   // [2048][1536] bf16
    const ushort* __restrict__ wb,   // [3][1536][1536] bf16
    const float*  __restrict__ cs,   // [2048][64] cos|sin table
    ushort* __restrict__ Qb, ushort* __restrict__ Kb, ushort* __restrict__ Vt)
{
    const int tm = blockIdx.x;
    const int tn = blockIdx.y;
    const int z  = blockIdx.z;
    const ushort* W = wb + (size_t)z * (D_MODEL * (size_t)D_MODEL);

    __shared__ __align__(16) ushort As[128 * 32];
    __shared__ __align__(16) ushort Bs[128 * 32];

    const int tid  = threadIdx.x;
    const int wave = tid >> 6;
    const int lane = tid & 63;

    const int srow = wave * 32 + (lane >> 2);
    const int scol = (lane & 3) * 8;
    const ushort* gA0 = xb + (size_t)(tm * 128 + srow) * D_MODEL + scol;
    const ushort* gA1 = gA0 + (size_t)16 * D_MODEL;
    const ushort* gB0 = W  + (size_t)(tn * 128 + srow) * D_MODEL + scol;
    const ushort* gB1 = gB0 + (size_t)16 * D_MODEL;
    ushort* lA0 = &As[wave * 1024];
    ushort* lA1 = &As[wave * 1024 + 512];
    ushort* lB0 = &Bs[wave * 1024];
    ushort* lB1 = &Bs[wave * 1024 + 512];

    const int wm = (wave >> 1) * 64;
    const int wn = (wave & 1) * 64;
    const int lrow  = lane & 15;
    const int quadk = (lane >> 4) * 8;

    floatx4 acc[4][4];
#pragma unroll
    for (int i = 0; i < 4; ++i)
#pragma unroll
        for (int j = 0; j < 4; ++j)
            acc[i][j] = (floatx4){0.f, 0.f, 0.f, 0.f};

    for (int kt = 0; kt < D_MODEL / 32; ++kt) {
        __syncthreads();
        ASYNC_COPY16(gA0 + kt * 32, lA0);
        ASYNC_COPY16(gA1 + kt * 32, lA1);
        ASYNC_COPY16(gB0 + kt * 32, lB0);
        ASYNC_COPY16(gB1 + kt * 32, lB1);
        __syncthreads();

        short8 af[4], bf[4];
#pragma unroll
        for (int i = 0; i < 4; ++i) af[i] = *(const short8*)(&As[(wm + i * 16 + lrow) * 32 + quadk]);
#pragma unroll
        for (int j = 0; j < 4; ++j) bf[j] = *(const short8*)(&Bs[(wn + j * 16 + lrow) * 32 + quadk]);
#pragma unroll
        for (int i = 0; i < 4; ++i)
#pragma unroll
            for (int j = 0; j < 4; ++j)
                acc[i][j] = __builtin_amdgcn_mfma_f32_16x16x32_bf16(af[i], bf[j], acc[i][j], 0, 0, 0);
    }

    const int r0 = (lane >> 4) * 4;
    const int c0 = lane & 15;
    if (z < 2) {
        ushort* O = (z == 0) ? Qb : Kb;
        // Q pre-scale: 0.125 (softmax) * log2(e) (exp2 domain)
        const float qscale = (z == 0) ? 0.18033688011112042f : 1.0f;
#pragma unroll
        for (int i = 0; i < 4; ++i) {
#pragma unroll
            for (int j = 0; j < 2; ++j) {
                const int col = tn * 128 + wn + j * 16 + c0;
                const int h = col >> 6, d0 = col & 63;
#pragma unroll
                for (int r = 0; r < 4; ++r) {
                    const int row = tm * 128 + wm + i * 16 + r0 + r;
                    const float c  = cs[row * 64 + d0];
                    const float sn = cs[row * 64 + 32 + d0];
                    const float x0 = acc[i][j][r];
                    const float x1 = acc[i][j + 2][r];
                    const size_t base = ((size_t)h * S_LEN + row) * HDIM;
                    O[base + d0]      = f32_to_bf16((x0 * c - x1 * sn) * qscale);
                    O[base + d0 + 32] = f32_to_bf16((x1 * c + x0 * sn) * qscale);
                }
            }
        }
    } else {
#pragma unroll
        for (int i = 0; i < 4; ++i) {
#pragma unroll
            for (int j = 0; j < 4; ++j) {
                int col = tn * 128 + wn + j * 16 + c0;
                int h = col >> 6, d = col & 63;
                int row0 = tm * 128 + wm + i * 16 + r0;
                ushort4 o;
                o.x = f32_to_bf16(acc[i][j][0]);
                o.y = f32_to_bf16(acc[i][j][1]);
                o.z = f32_to_bf16(acc[i][j][2]);
                o.w = f32_to_bf16(acc[i][j][3]);
                *(ushort4*)&Vt[((size_t)h * HDIM + d) * S_LEN + row0] = o;
            }
        }
    }
}

// ---------------- flash attention: S^T formulation ----------------
// S^T = K·Q^T so each lane owns ALL scores of one query (l16) -> softmax
// reduction is in-lane VALU + 2 shfls instead of 32 serial shfls.
// 2 k-tiles (128 keys) per round. Per-tile wave-uniform mask modes.
// NOTE: no min-waves clamp — __launch_bounds__(256,4) forced VGPR=64 and
// spilled S[8] to scratch (+42MB HBM writes/dispatch, R7 post-mortem).
__global__ __launch_bounds__(256) void flash_attn_kernel(
    const ushort* __restrict__ Qb,   // [H][S][64] bf16 roped, pre-scaled
    const ushort* __restrict__ Kb,   // [H][S][64] bf16 roped
    const ushort* __restrict__ Vt,   // [H][64][S] bf16
    const float* __restrict__ spikef,// [S] 0.0/1.0
    float* __restrict__ out)         // [S][1536]
{
    // XCD-aware remap: each XCD owns 3 whole heads (K/V set ~3MB < 4MB L2)
    const int lb  = blockIdx.x + (blockIdx.y << 5);  // 0..767
    const int h   = (lb & 7) * 3 + ((lb >> 3) >> 5);
    const int qt  = (lb >> 3) & 31;
    const int qs  = qt * 64;
    const int tid  = threadIdx.x;
    const int wave = tid >> 6;
    const int lane = tid & 63;
    const int quad = lane >> 4;
    const int l16  = lane & 15;

    __shared__ __align__(16) ushort Pst[4][16 * 136];   // per-wave P [q][k0..127], stride 136

    const size_t krow = (size_t)h * S_LEN;

    // Q B-fragments (n = q = l16)
    const ushort* Qp = Qb + (krow + qs + wave * 16 + l16) * HDIM + quad * 8;
    const short8 qf0 = *(const short8*)(Qp);
    const short8 qf1 = *(const short8*)(Qp + 32);

    const int q_lane = qs + wave * 16 + l16;   // the query this lane's softmax owns

    float m_i = -INFINITY, l_i = 0.f;
    floatx4 Oacc[4];
#pragma unroll
    for (int j2 = 0; j2 < 4; ++j2) Oacc[j2] = (floatx4){0.f, 0.f, 0.f, 0.f};

    const int lo = (qs > WINDOW ? qs - WINDOW : 0) >> 6;
    const int has_anchor = (lo > 0) ? 1 : 0;
    const int nt = (qt - lo + 1) + has_anchor;
    const int nr = (nt + 1) >> 1;

    ushort* myP = Pst[wave];

    for (int ri = 0; ri < nr; ++ri) {
        const int iA = 2 * ri, iB = 2 * ri + 1;
        const int tA = has_anchor ? (iA == 0 ? 0 : lo + iA - 1) : iA;
        const int liveB = (iB < nt) ? 1 : 0;
        const int tB = liveB ? (has_anchor ? (lo + iB - 1) : iB) : tA;

        // ---- S^T = K · Q^T : 8 frags (f<4: tile A, f>=4: tile B) ----
        floatx4 S[8];
        float4 sp[8];
#pragma unroll
        for (int f = 0; f < 8; ++f) {
            const int t = (f < 4) ? tA : tB;
            const int ks = t * 64 + (f & 3) * 16;
            const ushort* Kp = Kb + (krow + ks + l16) * HDIM + quad * 8;
            short8 kf0 = *(const short8*)(Kp);
            short8 kf1 = *(const short8*)(Kp + 32);
            sp[f] = *(const float4*)(spikef + ks + quad * 4);
            floatx4 a = (floatx4){0.f, 0.f, 0.f, 0.f};
            a = __builtin_amdgcn_mfma_f32_16x16x32_bf16(kf0, qf0, a, 0, 0, 0);
            a = __builtin_amdgcn_mfma_f32_16x16x32_bf16(kf1, qf1, a, 0, 0, 0);
            S[f] = a;
        }

        // ---- max over lane's 32 raw scores (valid superset: safe stabilizer) ----
        float fm[8];
#pragma unroll
        for (int f = 0; f < 8; ++f)
            fm[f] = fmaxf(fmaxf(S[f][0], S[f][1]), fmaxf(S[f][2], S[f][3]));
        float mx = fmaxf(fmaxf(fmaxf(fm[0], fm[1]), fmaxf(fm[2], fm[3])),
                         fmaxf(fmaxf(fm[4], fm[5]), fmaxf(fm[6], fm[7])));
        mx = fmaxf(mx, __shfl_xor(mx, 16));
        mx = fmaxf(mx, __shfl_xor(mx, 32));
        const float mnew = fmaxf(m_i, mx);
        const float aexp = exp2f(m_i - mnew);   // m_i=-inf first round -> 0

        // ---- masks (wave-uniform mode per tile) + exp2 + weights ----
        // mode: 0=interior 1=diag(k<=q) 2=window-edge 3=anchor(k<4) 4=dead
        int modeA, modeB;
        {
            modeA = (tA == qt) ? 1 : ((has_anchor && tA == 0) ? 3 :
                    ((qs + 63 - tA * 64 > WINDOW) ? 2 : 0));
            modeB = !liveB ? 4 : ((tB == qt) ? 1 : ((has_anchor && tB == 0) ? 3 :
                    ((qs + 63 - tB * 64 > WINDOW) ? 2 : 0)));
        }
        float rsum = 0.f;
#pragma unroll
        for (int f = 0; f < 8; ++f) {
            const int t = (f < 4) ? tA : tB;
            const int mode = (f < 4) ? modeA : modeB;
            const int kb = t * 64 + (f & 3) * 16 + quad * 4;
#pragma unroll
            for (int r = 0; r < 4; ++r) {
                const int k = kb + r;
                float v;
                if (mode == 0)      v = 1.f;
                else if (mode == 1) v = (k <= q_lane) ? 1.f : 0.f;
                else if (mode == 2) v = ((k >= q_lane - WINDOW) || (k < NANCH)) ? 1.f : 0.f;
                else if (mode == 3) v = (k < NANCH) ? 1.f : 0.f;
                else                v = 0.f;
                const float sv = (r == 0) ? sp[f].x : (r == 1) ? sp[f].y : (r == 2) ? sp[f].z : sp[f].w;
                const float w = exp2f(S[f][r] - mnew) * v * sv;
                S[f][r] = w;
                rsum += w;
            }
        }
        rsum += __shfl_xor(rsum, 16);
        rsum += __shfl_xor(rsum, 32);
        l_i = l_i * aexp + rsum;
        m_i = mnew;

        // ---- redistribute alpha to O C-layout rows (q = quad*4+r) ----
        float ar[4];
#pragma unroll
        for (int r = 0; r < 4; ++r)
            ar[r] = __int_as_float(__builtin_amdgcn_ds_bpermute((quad * 4 + r) * 4,
                                                                __float_as_int(aexp)));
#pragma unroll
        for (int j2 = 0; j2 < 4; ++j2)
#pragma unroll
            for (int r = 0; r < 4; ++r)
                Oacc[j2][r] *= ar[r];

        // ---- pack P (bf16 truncation) -> LDS [q=l16][kcol], 8 x b64 ----
#pragma unroll
        for (int f = 0; f < 8; ++f) {
            uint32_t p01 = (__float_as_uint(S[f][0]) >> 16) | (__float_as_uint(S[f][1]) & 0xFFFF0000u);
            uint32_t p23 = (__float_as_uint(S[f][2]) >> 16) | (__float_as_uint(S[f][3]) & 0xFFFF0000u);
            uint2 pk; pk.x = p01; pk.y = p23;
            *(uint2*)(myP + l16 * 136 + f * 16 + quad * 4) = pk;
        }

        // ---- P @ V : O[q][d] += P[q][k] V[k][d] ----
#pragma unroll
        for (int c = 0; c < 4; ++c) {
            const short8 pA = *(const short8*)(myP + l16 * 136 + c * 32 + quad * 8);
            const int kg = ((c < 2) ? (tA * 64 + c * 32) : (tB * 64 + (c - 2) * 32)) + quad * 8;
#pragma unroll
            for (int j2 = 0; j2 < 4; ++j2) {
                const short8 vf = *(const short8*)(Vt + ((size_t)h * HDIM + j2 * 16 + l16) * S_LEN + kg);
                Oacc[j2] = __builtin_amdgcn_mfma_f32_16x16x32_bf16(pA, vf, Oacc[j2], 0, 0, 0);
            }
        }
    }

    // ---- epilogue ----
    float linv[4];
#pragma unroll
    for (int r = 0; r < 4; ++r) {
        const float lr = __int_as_float(__builtin_amdgcn_ds_bpermute((quad * 4 + r) * 4,
                                                                     __float_as_int(l_i)));
        const int qrow = qs + wave * 16 + quad * 4 + r;
        linv[r] = (lr > 0.f && spikef[qrow] != 0.f) ? (1.0f / lr) : 0.f;
    }
#pragma unroll
    for (int r = 0; r < 4; ++r) {
        const int qrow = qs + wave * 16 + quad * 4 + r;
#pragma unroll
        for (int j2 = 0; j2 < 4; ++j2)
            out[(size_t)qrow * D_MODEL + h * HDIM + j2 * 16 + l16] = Oacc[j2][r] * linv[r];
    }
}

extern "C" void kernel_launch(void* const* d_in, const int* in_sizes, int n_in,
                              void* d_out, int out_size, void* d_ws, size_t ws_size,
                              hipStream_t stream) {
    const float* x     = (const float*)d_in[0];
    const uint8_t* spike_raw = (const uint8_t*)d_in[1];
    const float* Wq    = (const float*)d_in[2];
    const float* Wk    = (const float*)d_in[3];
    const float* Wv    = (const float*)d_in[4];
    float* out = (float*)d_out;

    const size_t xb_elems = (size_t)S_LEN * D_MODEL;
    const size_t w_elems  = (size_t)D_MODEL * D_MODEL;
    const size_t hs_elems = (size_t)NH * S_LEN * HDIM;

    char* ws = (char*)d_ws;
    size_t off = 0;
    ushort* xb = (ushort*)(ws + off); off += xb_elems * 2;
    ushort* wb = (ushort*)(ws + off); off += 3 * w_elems * 2;
    ushort* Qb = (ushort*)(ws + off); off += hs_elems * 2;
    ushort* Kb = (ushort*)(ws + off); off += hs_elems * 2;
    ushort* Vt = (ushort*)(ws + off); off += hs_elems * 2;
    float*  cst = (float*)(ws + off); off += (size_t)S_LEN * 64 * 4;
    float* spike_f = (float*)(ws + off); off += S_LEN * 4;
    if (ws_size < off) return;

    // 0) RoPE table + spike normalize
    prep_kernel<<<257, 256, 0, stream>>>(spike_raw, spike_f, cst);

    // 1) fp32 -> bf16 (x, Wq, Wk, Wv)
    {
        int xq4 = (int)(xb_elems / 4);
        int wq4 = (int)(w_elems / 4);
        f2bf4_kernel<<<dim3((xq4 + 255) / 256, 4), 256, 0, stream>>>(
            x, Wq, Wk, Wv, xb, wb, xq4, wq4);
    }

    // 2) QKV projections + fused RoPE
    gemm_qkv_kernel<<<dim3(S_LEN / 128, D_MODEL / 128, 3), 256, 0, stream>>>(
        xb, wb, cst, Qb, Kb, Vt);

    // 3) flash attention (S^T formulation)
    flash_attn_kernel<<<dim3(S_LEN / 64, NH), 256, 0, stream>>>(Qb, Kb, Vt, spike_f, out);
}

// Round 9
// 228.632 us; speedup vs baseline: 1.0589x; 1.0350x over previous
//
#include <hip/hip_runtime.h>
#include <cstdint>
#include <cstddef>

#define S_LEN   2048
#define D_MODEL 1536
#define NH      24
#define HDIM    64
#define WINDOW  512
#define NANCH   4

typedef __attribute__((ext_vector_type(8))) short short8;
typedef __attribute__((ext_vector_type(4))) float floatx4;

#define ASYNC_COPY16(g, l) \
    __builtin_amdgcn_global_load_lds((const __attribute__((address_space(1))) uint32_t*)(g), \
                                     (__attribute__((address_space(3))) uint32_t*)(l), 16, 0, 0)

static __device__ __forceinline__ ushort f32_to_bf16(float f) {
    uint32_t u = __float_as_uint(f);
    uint32_t r = (u + 0x7FFFu + ((u >> 16) & 1u)) >> 16;
    return (ushort)r;
}

// ---------------- prep: RoPE cos/sin table + spike mask normalize (float) ----------------
__global__ __launch_bounds__(256) void prep_kernel(
    const uint8_t* __restrict__ raw, float* __restrict__ normf, float* __restrict__ cs) {
    if (blockIdx.x < 256) {
        int idx = blockIdx.x * 256 + threadIdx.x;   // 65536 = s*32 + i
        int s = idx >> 5, i = idx & 31;
        float inv_freq = expf(-(float)i * 0.2878231366242557f); // ln(10000)/32
        float c, sn;
        sincosf((float)s * inv_freq, &sn, &c);
        cs[s * 64 + i]      = c;
        cs[s * 64 + 32 + i] = sn;
        return;
    }
    __shared__ int sh[2];
    if (threadIdx.x == 0) { sh[0] = 0; sh[1] = 0; }
    __syncthreads();
    int f = 0, nz = 0;
    for (int i = threadIdx.x; i < S_LEN; i += 256) {
        uint8_t b = raw[i];
        if ((i & 3) == 3 && b == 0x3f) f++;          // 1.0f high byte
        if ((i & 3) != 0 && b != 0)    nz++;
    }
    if (f)  atomicAdd(&sh[0], f);
    if (nz) atomicAdd(&sh[1], nz);
    __syncthreads();
    const int mode = (sh[0] > 0) ? 2 : ((sh[1] > 0) ? 1 : 0);  // 2=f32 1=u8 0=i32
    for (int i = threadIdx.x; i < S_LEN; i += 256) {
        int v;
        if (mode == 2)      v = (((const float*)raw)[i] != 0.0f) ? 1 : 0;
        else if (mode == 1) v = raw[i] ? 1 : 0;
        else                v = (((const int*)raw)[i] != 0) ? 1 : 0;
        normf[i] = v ? 1.0f : 0.0f;
    }
}

// ---------------- fp32 -> bf16 convert: x + Wq + Wk + Wv in one launch ----------------
__global__ void f2bf4_kernel(const float* __restrict__ x,
                             const float* __restrict__ wq, const float* __restrict__ wk,
                             const float* __restrict__ wv,
                             ushort* __restrict__ xb, ushort* __restrict__ wb,
                             int xq4, int wq4) {
    const int which = blockIdx.y;
    const size_t w_elems = (size_t)D_MODEL * D_MODEL;
    const float* src; ushort* dst; int n4;
    if (which == 0)      { src = x;  dst = xb;               n4 = xq4; }
    else if (which == 1) { src = wq; dst = wb;               n4 = wq4; }
    else if (which == 2) { src = wk; dst = wb + w_elems;     n4 = wq4; }
    else                 { src = wv; dst = wb + 2 * w_elems; n4 = wq4; }
    int i = blockIdx.x * blockDim.x + threadIdx.x;
    if (i >= n4) return;
    float4 v = ((const float4*)src)[i];
    ushort4 o;
    o.x = f32_to_bf16(v.x);
    o.y = f32_to_bf16(v.y);
    o.z = f32_to_bf16(v.z);
    o.w = f32_to_bf16(v.w);
    ((ushort4*)dst)[i] = o;
}

// ---------------- QKV projection + fused RoPE ----------------
// z=0 -> Qb bf16 (roped, pre-scaled 0.125*log2e for exp2-domain softmax);
// z=1 -> Kb bf16 (roped); z=2 -> Vt bf16 [H][64][S]
__global__ __launch_bounds__(256) void gemm_qkv_kernel(
    const ushort* __restrict__ xb,   // [2048][1536] bf16
    const ushort* __restrict__ wb,   // [3][1536][1536] bf16
    const float*  __restrict__ cs,   // [2048][64] cos|sin table
    ushort* __restrict__ Qb, ushort* __restrict__ Kb, ushort* __restrict__ Vt)
{
    const int tm = blockIdx.x;
    const int tn = blockIdx.y;
    const int z  = blockIdx.z;
    const ushort* W = wb + (size_t)z * (D_MODEL * (size_t)D_MODEL);

    __shared__ __align__(16) ushort As[128 * 32];
    __shared__ __align__(16) ushort Bs[128 * 32];

    const int tid  = threadIdx.x;
    const int wave = tid >> 6;
    const int lane = tid & 63;

    const int srow = wave * 32 + (lane >> 2);
    const int scol = (lane & 3) * 8;
    const ushort* gA0 = xb + (size_t)(tm * 128 + srow) * D_MODEL + scol;
    const ushort* gA1 = gA0 + (size_t)16 * D_MODEL;
    const ushort* gB0 = W  + (size_t)(tn * 128 + srow) * D_MODEL + scol;
    const ushort* gB1 = gB0 + (size_t)16 * D_MODEL;
    ushort* lA0 = &As[wave * 1024];
    ushort* lA1 = &As[wave * 1024 + 512];
    ushort* lB0 = &Bs[wave * 1024];
    ushort* lB1 = &Bs[wave * 1024 + 512];

    const int wm = (wave >> 1) * 64;
    const int wn = (wave & 1) * 64;
    const int lrow  = lane & 15;
    const int quadk = (lane >> 4) * 8;

    floatx4 acc[4][4];
#pragma unroll
    for (int i = 0; i < 4; ++i)
#pragma unroll
        for (int j = 0; j < 4; ++j)
            acc[i][j] = (floatx4){0.f, 0.f, 0.f, 0.f};

    for (int kt = 0; kt < D_MODEL / 32; ++kt) {
        __syncthreads();
        ASYNC_COPY16(gA0 + kt * 32, lA0);
        ASYNC_COPY16(gA1 + kt * 32, lA1);
        ASYNC_COPY16(gB0 + kt * 32, lB0);
        ASYNC_COPY16(gB1 + kt * 32, lB1);
        __syncthreads();

        short8 af[4], bf[4];
#pragma unroll
        for (int i = 0; i < 4; ++i) af[i] = *(const short8*)(&As[(wm + i * 16 + lrow) * 32 + quadk]);
#pragma unroll
        for (int j = 0; j < 4; ++j) bf[j] = *(const short8*)(&Bs[(wn + j * 16 + lrow) * 32 + quadk]);
#pragma unroll
        for (int i = 0; i < 4; ++i)
#pragma unroll
            for (int j = 0; j < 4; ++j)
                acc[i][j] = __builtin_amdgcn_mfma_f32_16x16x32_bf16(af[i], bf[j], acc[i][j], 0, 0, 0);
    }

    const int r0 = (lane >> 4) * 4;
    const int c0 = lane & 15;
    if (z < 2) {
        ushort* O = (z == 0) ? Qb : Kb;
        // Q pre-scale: 0.125 (softmax) * log2(e) (exp2 domain)
        const float qscale = (z == 0) ? 0.18033688011112042f : 1.0f;
#pragma unroll
        for (int i = 0; i < 4; ++i) {
#pragma unroll
            for (int j = 0; j < 2; ++j) {
                const int col = tn * 128 + wn + j * 16 + c0;
                const int h = col >> 6, d0 = col & 63;
#pragma unroll
                for (int r = 0; r < 4; ++r) {
                    const int row = tm * 128 + wm + i * 16 + r0 + r;
                    const float c  = cs[row * 64 + d0];
                    const float sn = cs[row * 64 + 32 + d0];
                    const float x0 = acc[i][j][r];
                    const float x1 = acc[i][j + 2][r];
                    const size_t base = ((size_t)h * S_LEN + row) * HDIM;
                    O[base + d0]      = f32_to_bf16((x0 * c - x1 * sn) * qscale);
                    O[base + d0 + 32] = f32_to_bf16((x1 * c + x0 * sn) * qscale);
                }
            }
        }
    } else {
#pragma unroll
        for (int i = 0; i < 4; ++i) {
#pragma unroll
            for (int j = 0; j < 4; ++j) {
                int col = tn * 128 + wn + j * 16 + c0;
                int h = col >> 6, d = col & 63;
                int row0 = tm * 128 + wm + i * 16 + r0;
                ushort4 o;
                o.x = f32_to_bf16(acc[i][j][0]);
                o.y = f32_to_bf16(acc[i][j][1]);
                o.z = f32_to_bf16(acc[i][j][2]);
                o.w = f32_to_bf16(acc[i][j][3]);
                *(ushort4*)&Vt[((size_t)h * HDIM + d) * S_LEN + row0] = o;
            }
        }
    }
}

// ---------------- flash attention: S^T formulation, 1 wave / 16 queries ----------------
// 64-thread workgroups: 3072 blocks (12/CU) for latency hiding + load balance.
// Each lane owns all scores of one query (l16); softmax reduction is in-lane
// VALU + 2 shfls. 2 k-tiles (128 keys) per round, wave-uniform mask modes.
__global__ __launch_bounds__(64) void flash_attn_kernel(
    const ushort* __restrict__ Qb,   // [H][S][64] bf16 roped, pre-scaled
    const ushort* __restrict__ Kb,   // [H][S][64] bf16 roped
    const ushort* __restrict__ Vt,   // [H][64][S] bf16
    const float* __restrict__ spikef,// [S] 0.0/1.0
    float* __restrict__ out)         // [S][1536]
{
    // XCD-aware remap: lb&7 = XCD slot; each XCD owns 3 whole heads
    const int lb   = blockIdx.x + (blockIdx.y << 7);  // 0..3071
    const int h    = (lb & 7) * 3 + ((lb >> 3) >> 7);
    const int qt16 = (lb >> 3) & 127;
    const int qs   = qt16 * 16;
    const int lane = threadIdx.x & 63;
    const int quad = lane >> 4;
    const int l16  = lane & 15;

    __shared__ __align__(16) ushort Pst[16 * 136];   // P [q][k0..127], stride 136

    const size_t krow = (size_t)h * S_LEN;

    // Q B-fragments (n = q = l16)
    const ushort* Qp = Qb + (krow + qs + l16) * HDIM + quad * 8;
    const short8 qf0 = *(const short8*)(Qp);
    const short8 qf1 = *(const short8*)(Qp + 32);

    const int q_lane = qs + l16;   // the query this lane's softmax owns

    float m_i = -INFINITY, l_i = 0.f;
    floatx4 Oacc[4];
#pragma unroll
    for (int j2 = 0; j2 < 4; ++j2) Oacc[j2] = (floatx4){0.f, 0.f, 0.f, 0.f};

    const int qtt = (qs + 15) >> 6;                   // diag tile (64-key granularity)
    const int lo = (qs > WINDOW ? qs - WINDOW : 0) >> 6;
    const int has_anchor = (lo > 0) ? 1 : 0;
    const int nt = (qtt - lo + 1) + has_anchor;
    const int nr = (nt + 1) >> 1;

    for (int ri = 0; ri < nr; ++ri) {
        const int iA = 2 * ri, iB = 2 * ri + 1;
        const int tA = has_anchor ? (iA == 0 ? 0 : lo + iA - 1) : iA;
        const int liveB = (iB < nt) ? 1 : 0;
        const int tB = liveB ? (has_anchor ? (lo + iB - 1) : iB) : tA;

        // ---- S^T = K · Q^T : 8 frags (f<4: tile A, f>=4: tile B) ----
        floatx4 S[8];
        float4 sp[8];
#pragma unroll
        for (int f = 0; f < 8; ++f) {
            const int t = (f < 4) ? tA : tB;
            const int ks = t * 64 + (f & 3) * 16;
            const ushort* Kp = Kb + (krow + ks + l16) * HDIM + quad * 8;
            short8 kf0 = *(const short8*)(Kp);
            short8 kf1 = *(const short8*)(Kp + 32);
            sp[f] = *(const float4*)(spikef + ks + quad * 4);
            floatx4 a = (floatx4){0.f, 0.f, 0.f, 0.f};
            a = __builtin_amdgcn_mfma_f32_16x16x32_bf16(kf0, qf0, a, 0, 0, 0);
            a = __builtin_amdgcn_mfma_f32_16x16x32_bf16(kf1, qf1, a, 0, 0, 0);
            S[f] = a;
        }

        // ---- max over lane's 32 raw scores (valid superset: safe stabilizer) ----
        float fm[8];
#pragma unroll
        for (int f = 0; f < 8; ++f)
            fm[f] = fmaxf(fmaxf(S[f][0], S[f][1]), fmaxf(S[f][2], S[f][3]));
        float mx = fmaxf(fmaxf(fmaxf(fm[0], fm[1]), fmaxf(fm[2], fm[3])),
                         fmaxf(fmaxf(fm[4], fm[5]), fmaxf(fm[6], fm[7])));
        mx = fmaxf(mx, __shfl_xor(mx, 16));
        mx = fmaxf(mx, __shfl_xor(mx, 32));
        const float mnew = fmaxf(m_i, mx);
        const float aexp = exp2f(m_i - mnew);   // m_i=-inf first round -> 0

        // ---- masks (wave-uniform mode per tile) + exp2 + weights ----
        // mode: 0=interior 1=diag(k<=q) 2=window-edge 3=anchor(k<4) 4=dead
        int modeA, modeB;
        {
            modeA = (tA == qtt) ? 1 : ((has_anchor && tA == 0) ? 3 :
                    ((qs + 15 - tA * 64 > WINDOW) ? 2 : 0));
            modeB = !liveB ? 4 : ((tB == qtt) ? 1 : ((has_anchor && tB == 0) ? 3 :
                    ((qs + 15 - tB * 64 > WINDOW) ? 2 : 0)));
        }
        float rsum = 0.f;
#pragma unroll
        for (int f = 0; f < 8; ++f) {
            const int t = (f < 4) ? tA : tB;
            const int mode = (f < 4) ? modeA : modeB;
            const int kb = t * 64 + (f & 3) * 16 + quad * 4;
#pragma unroll
            for (int r = 0; r < 4; ++r) {
                const int k = kb + r;
                float v;
                if (mode == 0)      v = 1.f;
                else if (mode == 1) v = (k <= q_lane) ? 1.f : 0.f;
                else if (mode == 2) v = ((k >= q_lane - WINDOW) || (k < NANCH)) ? 1.f : 0.f;
                else if (mode == 3) v = (k < NANCH) ? 1.f : 0.f;
                else                v = 0.f;
                const float sv = (r == 0) ? sp[f].x : (r == 1) ? sp[f].y : (r == 2) ? sp[f].z : sp[f].w;
                const float w = exp2f(S[f][r] - mnew) * v * sv;
                S[f][r] = w;
                rsum += w;
            }
        }
        rsum += __shfl_xor(rsum, 16);
        rsum += __shfl_xor(rsum, 32);
        l_i = l_i * aexp + rsum;
        m_i = mnew;

        // ---- redistribute alpha to O C-layout rows (q = quad*4+r) ----
        float ar[4];
#pragma unroll
        for (int r = 0; r < 4; ++r)
            ar[r] = __int_as_float(__builtin_amdgcn_ds_bpermute((quad * 4 + r) * 4,
                                                                __float_as_int(aexp)));
#pragma unroll
        for (int j2 = 0; j2 < 4; ++j2)
#pragma unroll
            for (int r = 0; r < 4; ++r)
                Oacc[j2][r] *= ar[r];

        // ---- pack P (bf16 truncation) -> LDS [q=l16][kcol], 8 x b64 ----
#pragma unroll
        for (int f = 0; f < 8; ++f) {
            uint32_t p01 = (__float_as_uint(S[f][0]) >> 16) | (__float_as_uint(S[f][1]) & 0xFFFF0000u);
            uint32_t p23 = (__float_as_uint(S[f][2]) >> 16) | (__float_as_uint(S[f][3]) & 0xFFFF0000u);
            uint2 pk; pk.x = p01; pk.y = p23;
            *(uint2*)(Pst + l16 * 136 + f * 16 + quad * 4) = pk;
        }

        // ---- P @ V : O[q][d] += P[q][k] V[k][d] ----
#pragma unroll
        for (int c = 0; c < 4; ++c) {
            const short8 pA = *(const short8*)(Pst + l16 * 136 + c * 32 + quad * 8);
            const int kg = ((c < 2) ? (tA * 64 + c * 32) : (tB * 64 + (c - 2) * 32)) + quad * 8;
#pragma unroll
            for (int j2 = 0; j2 < 4; ++j2) {
                const short8 vf = *(const short8*)(Vt + ((size_t)h * HDIM + j2 * 16 + l16) * S_LEN + kg);
                Oacc[j2] = __builtin_amdgcn_mfma_f32_16x16x32_bf16(pA, vf, Oacc[j2], 0, 0, 0);
            }
        }
    }

    // ---- epilogue ----
    float linv[4];
#pragma unroll
    for (int r = 0; r < 4; ++r) {
        const float lr = __int_as_float(__builtin_amdgcn_ds_bpermute((quad * 4 + r) * 4,
                                                                     __float_as_int(l_i)));
        const int qrow = qs + quad * 4 + r;
        linv[r] = (lr > 0.f && spikef[qrow] != 0.f) ? (1.0f / lr) : 0.f;
    }
#pragma unroll
    for (int r = 0; r < 4; ++r) {
        const int qrow = qs + quad * 4 + r;
#pragma unroll
        for (int j2 = 0; j2 < 4; ++j2)
            out[(size_t)qrow * D_MODEL + h * HDIM + j2 * 16 + l16] = Oacc[j2][r] * linv[r];
    }
}

extern "C" void kernel_launch(void* const* d_in, const int* in_sizes, int n_in,
                              void* d_out, int out_size, void* d_ws, size_t ws_size,
                              hipStream_t stream) {
    const float* x     = (const float*)d_in[0];
    const uint8_t* spike_raw = (const uint8_t*)d_in[1];
    const float* Wq    = (const float*)d_in[2];
    const float* Wk    = (const float*)d_in[3];
    const float* Wv    = (const float*)d_in[4];
    float* out = (float*)d_out;

    const size_t xb_elems = (size_t)S_LEN * D_MODEL;
    const size_t w_elems  = (size_t)D_MODEL * D_MODEL;
    const size_t hs_elems = (size_t)NH * S_LEN * HDIM;

    char* ws = (char*)d_ws;
    size_t off = 0;
    ushort* xb = (ushort*)(ws + off); off += xb_elems * 2;
    ushort* wb = (ushort*)(ws + off); off += 3 * w_elems * 2;
    ushort* Qb = (ushort*)(ws + off); off += hs_elems * 2;
    ushort* Kb = (ushort*)(ws + off); off += hs_elems * 2;
    ushort* Vt = (ushort*)(ws + off); off += hs_elems * 2;
    float*  cst = (float*)(ws + off); off += (size_t)S_LEN * 64 * 4;
    float* spike_f = (float*)(ws + off); off += S_LEN * 4;
    if (ws_size < off) return;

    // 0) RoPE table + spike normalize
    prep_kernel<<<257, 256, 0, stream>>>(spike_raw, spike_f, cst);

    // 1) fp32 -> bf16 (x, Wq, Wk, Wv)
    {
        int xq4 = (int)(xb_elems / 4);
        int wq4 = (int)(w_elems / 4);
        f2bf4_kernel<<<dim3((xq4 + 255) / 256, 4), 256, 0, stream>>>(
            x, Wq, Wk, Wv, xb, wb, xq4, wq4);
    }

    // 2) QKV projections + fused RoPE
    gemm_qkv_kernel<<<dim3(S_LEN / 128, D_MODEL / 128, 3), 256, 0, stream>>>(
        xb, wb, cst, Qb, Kb, Vt);

    // 3) flash attention (S^T, 1-wave workgroups, 16 queries/wave)
    flash_attn_kernel<<<dim3(128, 24), 64, 0, stream>>>(Qb, Kb, Vt, spike_f, out);
}